// Round 1
// baseline (892.090 us; speedup 1.0000x reference)
//
#include <hip/hip_runtime.h>

// GraphHyperbolicVisitEncoderGlobal — MI355X fp16-MFMA implementation.
// Pipeline: logmap0 -> Ycat_k = Z0@P_k -> H = sum_k kernels[k]@Ycat_k + proj_b
//           -> 2x {QKV, flash-attn, Wo, LN, FF(gelu), LN} -> time-emb GEMM -> gather+mean.
// All matmuls: v_mfma_f32_16x16x32_f16, fp32 accumulate. fp32 softmax/LN/GELU.

using f16 = _Float16;
typedef f16   f16x8 __attribute__((ext_vector_type(8)));
typedef float f32x4 __attribute__((ext_vector_type(4)));

#define V_   4096
#define D_   128
#define NVIS 16384

union H4 { f16 h[4]; uint2 u; };

// ---------------- weight conversion (fp32 -> fp16 transposed, + bias concat) ----------------
struct CvtTask { const float* src; void* dst; int R, C, kind; }; // kind 0: dst[c*R+r]=(f16)src[r*C+c]; 1: f32 copy
struct CvtTasks { CvtTask t[24]; int n; };

__global__ __launch_bounds__(256) void cvt_kernel(CvtTasks T) {
  int tid0 = blockIdx.x * 256 + threadIdx.x;
  int stride = gridDim.x * 256;
  for (int i = 0; i < T.n; i++) {
    CvtTask tk = T.t[i];
    int total = tk.R * tk.C;
    for (int idx = tid0; idx < total; idx += stride) {
      int r = idx / tk.C, c = idx - r * tk.C;
      if (tk.kind == 0)
        ((f16*)tk.dst)[(long long)c * tk.R + r] = (f16)tk.src[idx];
      else
        ((float*)tk.dst)[idx] = tk.src[idx];
    }
  }
}

// ---------------- logmap0: Z0 = atanh(clip(|x|)) * x / clip(|x|) ----------------
__global__ __launch_bounds__(256) void logmap_kernel(const float* __restrict__ X, float* __restrict__ Z0) {
  int row = blockIdx.x * 4 + (threadIdx.x >> 6);
  int l = threadIdx.x & 63;
  const float* xr = X + (long long)row * D_;
  float a = xr[l], b = xr[l + 64];
  float ss = a * a + b * b;
  #pragma unroll
  for (int m = 1; m < 64; m <<= 1) ss += __shfl_xor(ss, m);
  float nrm = sqrtf(ss);
  float nc = fminf(fmaxf(nrm, 1e-7f), 1.0f - 1e-5f);
  float scale = atanhf(nc) / nc;
  float* zr = Z0 + (long long)row * D_;
  zr[l] = a * scale; zr[l + 64] = b * scale;
}

// ---------------- generic fp16-MFMA GEMM ----------------
// C[M,N](+bias,act) = A[M,K] (fp32, converted while staging) @ B[K,N] (as pre-transposed BT[N][K] fp16)
// block: 256 thr = 4 waves; tile BM=64 x BN=128, BK=64; wave tile 32x64.
struct GemmP {
  const float* A;  long long a_y, a_z;  int lda;
  const f16*  BT;  long long bt_y, bt_z; int ldbt;
  const float* bias; int bias_y, bias_z;         // may be null
  float* C;  long long c_y, c_z;   int ldc;
  f16*  CH;  long long ch_y, ch_z; int ldch;     // row-major fp16 copy
  f16*  CHT; long long cht_y, cht_z; int ldcht;  // transposed fp16 copy [N][M]
  int K;                                          // inner length per block (mult of 64)
};

template<int ACT, bool WC, bool WH, bool WHT>
__global__ __launch_bounds__(256) void gemm_kernel(GemmP p) {
  __shared__ alignas(16) f16 As[64][64];   // XOR-swizzled: col ^= (row&7)<<3
  __shared__ alignas(16) f16 Bs[128][64];  // idem
  int tid = threadIdx.x;
  int m0 = blockIdx.x * 64;
  long long by = blockIdx.y, bz = blockIdx.z;
  const float* A = p.A + by * p.a_y + bz * p.a_z + (long long)m0 * p.lda;
  const f16* BT  = p.BT + by * p.bt_y + bz * p.bt_z;

  int wid = tid >> 6, l = tid & 63;
  int lr = l & 15, lg = l >> 4;
  int wm = (wid & 1) * 32;
  int wn = (wid >> 1) * 64;

  f32x4 acc[2][4] = {};

  for (int kb = 0; kb < p.K; kb += 64) {
    __syncthreads();
    #pragma unroll
    for (int pi = 0; pi < 4; pi++) {            // stage A: 64x64 fp32 -> fp16
      int idx = pi * 256 + tid;
      int r = idx >> 4, c4 = (idx & 15) * 4;
      float4 v = *(const float4*)(A + (long long)r * p.lda + kb + c4);
      int cc = c4 ^ ((r & 7) << 3);
      H4 tmp; tmp.h[0] = (f16)v.x; tmp.h[1] = (f16)v.y; tmp.h[2] = (f16)v.z; tmp.h[3] = (f16)v.w;
      *(uint2*)&As[r][cc] = tmp.u;
    }
    #pragma unroll
    for (int pi = 0; pi < 4; pi++) {            // stage B: 128x64 fp16
      int idx = pi * 256 + tid;
      int n = idx >> 3, g8 = (idx & 7) * 8;
      f16x8 v = *(const f16x8*)(BT + (long long)n * p.ldbt + kb + g8);
      *(f16x8*)&Bs[n][g8 ^ ((n & 7) << 3)] = v;
    }
    __syncthreads();
    #pragma unroll
    for (int kk = 0; kk < 64; kk += 32) {
      f16x8 a[2], b[4];
      #pragma unroll
      for (int mt = 0; mt < 2; mt++) {
        int r = wm + mt * 16 + lr;
        a[mt] = *(const f16x8*)&As[r][(kk + lg * 8) ^ ((r & 7) << 3)];
      }
      #pragma unroll
      for (int nt = 0; nt < 4; nt++) {
        int n = wn + nt * 16 + lr;
        b[nt] = *(const f16x8*)&Bs[n][(kk + lg * 8) ^ ((n & 7) << 3)];
      }
      #pragma unroll
      for (int mt = 0; mt < 2; mt++)
        #pragma unroll
        for (int nt = 0; nt < 4; nt++)
          acc[mt][nt] = __builtin_amdgcn_mfma_f32_16x16x32_f16(a[mt], b[nt], acc[mt][nt], 0, 0, 0);
    }
  }

  const float* bias = p.bias ? p.bias + by * p.bias_y + bz * p.bias_z : nullptr;
  float* C = nullptr; f16* CH = nullptr; f16* CHT = nullptr;
  if (WC)  C   = p.C   + by * p.c_y   + bz * p.c_z   + (long long)m0 * p.ldc;
  if (WH)  CH  = p.CH  + by * p.ch_y  + bz * p.ch_z  + (long long)m0 * p.ldch;
  if (WHT) CHT = p.CHT + by * p.cht_y + bz * p.cht_z;

  #pragma unroll
  for (int nt = 0; nt < 4; nt++) {
    int n = wn + nt * 16 + lr;
    float bv = bias ? bias[n] : 0.0f;
    #pragma unroll
    for (int mt = 0; mt < 2; mt++) {
      H4 th;
      #pragma unroll
      for (int r = 0; r < 4; r++) {
        float val = acc[mt][nt][r] + bv;
        if (ACT == 1) val = 0.5f * val * (1.0f + erff(val * 0.70710678118654752f));
        int m = wm + mt * 16 + lg * 4 + r;
        if (WC) C[(long long)m * p.ldc + n] = val;
        if (WH) CH[(long long)m * p.ldch + n] = (f16)val;
        th.h[r] = (f16)val;
      }
      if (WHT)
        *(uint2*)&CHT[(long long)n * p.ldcht + m0 + wm + mt * 16 + lg * 4] = th.u;
    }
  }
}

// ---------------- combine diffusion partials: x = proj_b + sum Hp ----------------
__global__ __launch_bounds__(256) void combine_kernel(const float* __restrict__ Hp, const float* __restrict__ proj_b,
                                                      float* __restrict__ x) {
  int i = blockIdx.x * 256 + threadIdx.x;
  float s = proj_b[i & 127];
  #pragma unroll
  for (int j = 0; j < 12; j++) s += Hp[(long long)j * (V_ * D_) + i];
  x[i] = s;
}

// ---------------- flash attention: grid (V/64, NH), 4 waves, 16 q-rows/wave ----------------
__global__ __launch_bounds__(256) void attn_kernel(const f16* __restrict__ qh, const f16* __restrict__ kh,
                                                   const f16* __restrict__ vT, float* __restrict__ o) {
  __shared__ alignas(16) f16 Ks[64][40];      // [key][d] (+8 pad)
  __shared__ alignas(16) f16 Vs[32][72];      // [d][key] (+8 pad)
  __shared__ alignas(16) f16 Ps[4][16][72];   // per-wave P [q][key]
  int tid = threadIdx.x, w = tid >> 6, l = tid & 63, lr = l & 15, lg = l >> 4;
  int h = blockIdx.y, q0 = blockIdx.x * 64;
  const float sc = 0.17677669529663687f; // 1/sqrt(32)

  f16x8 aq = *(const f16x8*)&qh[(long long)(q0 + w * 16 + lr) * D_ + h * 32 + lg * 8];
  float mrow[4], lsum[4];
  f32x4 oacc[2] = {};
  #pragma unroll
  for (int r = 0; r < 4; r++) { mrow[r] = -1e30f; lsum[r] = 0.f; }
  const f32x4 vzero = {0.f, 0.f, 0.f, 0.f};

  for (int kt = 0; kt < V_ / 64; kt++) {
    int key0 = kt * 64;
    __syncthreads();
    {
      int key = tid >> 2, g8 = (tid & 3) * 8;
      *(f16x8*)&Ks[key][g8] = *(const f16x8*)&kh[(long long)(key0 + key) * D_ + h * 32 + g8];
      int dd = tid >> 3, kg = (tid & 7) * 8;
      *(f16x8*)&Vs[dd][kg] = *(const f16x8*)&vT[(long long)(h * 32 + dd) * V_ + key0 + kg];
    }
    __syncthreads();
    // S = Q K^T  (tile t covers keys key0+16t..+15)
    f32x4 s[4];
    #pragma unroll
    for (int t = 0; t < 4; t++) {
      f16x8 bk = *(const f16x8*)&Ks[t * 16 + lr][lg * 8];
      s[t] = __builtin_amdgcn_mfma_f32_16x16x32_f16(aq, bk, vzero, 0, 0, 0);
    }
    // online softmax; lane holds rows lg*4+r, key col = 16t+lr
    float pv[4][4];
    #pragma unroll
    for (int r = 0; r < 4; r++) {
      float sv0 = s[0][r] * sc, sv1 = s[1][r] * sc, sv2 = s[2][r] * sc, sv3 = s[3][r] * sc;
      float mx = fmaxf(fmaxf(sv0, sv1), fmaxf(sv2, sv3));
      #pragma unroll
      for (int msk = 1; msk < 16; msk <<= 1) mx = fmaxf(mx, __shfl_xor(mx, msk));
      float mn = fmaxf(mrow[r], mx);
      float alpha = expf(mrow[r] - mn);
      float e0 = expf(sv0 - mn), e1 = expf(sv1 - mn), e2 = expf(sv2 - mn), e3 = expf(sv3 - mn);
      pv[0][r] = e0; pv[1][r] = e1; pv[2][r] = e2; pv[3][r] = e3;
      float rs = e0 + e1 + e2 + e3;
      #pragma unroll
      for (int msk = 1; msk < 16; msk <<= 1) rs += __shfl_xor(rs, msk);
      lsum[r] = lsum[r] * alpha + rs;
      mrow[r] = mn;
      oacc[0][r] *= alpha; oacc[1][r] *= alpha;
    }
    #pragma unroll
    for (int t = 0; t < 4; t++)
      #pragma unroll
      for (int r = 0; r < 4; r++)
        Ps[w][lg * 4 + r][t * 16 + lr] = (f16)pv[t][r];
    // O += P V  (P as A-operand from LDS, V^T as B-operand)
    #pragma unroll
    for (int kc = 0; kc < 2; kc++) {
      f16x8 pa = *(const f16x8*)&Ps[w][lr][kc * 32 + lg * 8];
      #pragma unroll
      for (int t = 0; t < 2; t++) {
        f16x8 bvv = *(const f16x8*)&Vs[t * 16 + lr][kc * 32 + lg * 8];
        oacc[t] = __builtin_amdgcn_mfma_f32_16x16x32_f16(pa, bvv, oacc[t], 0, 0, 0);
      }
    }
  }
  #pragma unroll
  for (int t = 0; t < 2; t++)
    #pragma unroll
    for (int r = 0; r < 4; r++) {
      int q = q0 + w * 16 + lg * 4 + r;
      o[(long long)q * D_ + h * 32 + t * 16 + lr] = oacc[t][r] / lsum[r];
    }
}

// ---------------- residual + LayerNorm (in-place on x) ----------------
__global__ __launch_bounds__(256) void ln_kernel(float* __restrict__ x, const float* __restrict__ add,
                                                 const float* __restrict__ g, const float* __restrict__ b) {
  int row = blockIdx.x * 4 + (threadIdx.x >> 6);
  int l = threadIdx.x & 63;
  long long base = (long long)row * D_;
  float a = x[base + l] + add[base + l];
  float c = x[base + l + 64] + add[base + l + 64];
  float s = a + c, ss = a * a + c * c;
  #pragma unroll
  for (int m = 1; m < 64; m <<= 1) { s += __shfl_xor(s, m); ss += __shfl_xor(ss, m); }
  float mean = s * (1.0f / 128.0f);
  float var = ss * (1.0f / 128.0f) - mean * mean;
  float rstd = rsqrtf(var + 1e-5f);
  x[base + l]      = (a - mean) * rstd * g[l] + b[l];
  x[base + l + 64] = (c - mean) * rstd * g[l + 64] + b[l + 64];
}

// ---------------- time features: S = 1 - tanh(deltas/180*tf_W + tf_b)^2 ----------------
__global__ __launch_bounds__(256) void timefeat_kernel(const float* __restrict__ deltas, const float* __restrict__ tf_W,
                                                       const float* __restrict__ tf_b, float* __restrict__ S) {
  int i = blockIdx.x * 256 + threadIdx.x;
  int n = i >> 7, d = i & 127;
  float fr = deltas[n] * (1.0f / 180.0f) * tf_W[d] + tf_b[d];
  float t = tanhf(fr);
  S[i] = 1.0f - t * t;
}

// ---------------- ragged gather + masked mean; out += vis ----------------
__global__ __launch_bounds__(256) void gather_kernel(const int* __restrict__ visits, const int* __restrict__ pad_ptr,
                                                     const float* __restrict__ Hr, float* __restrict__ out) {
  __shared__ int vis[2][32];
  int tid = threadIdx.x;
  int pad = *pad_ptr;
  int nb = blockIdx.x * 2;
  if (tid < 64) { int s = tid >> 5, c = tid & 31; vis[s][c] = visits[(long long)(nb + s) * 32 + c]; }
  __syncthreads();
  int s = tid >> 7, d = tid & 127;
  float acc = 0.f; int cnt = 0;
  #pragma unroll 8
  for (int c = 0; c < 32; c++) {
    int idx = vis[s][c];
    if (idx != pad) { acc += Hr[(long long)idx * D_ + d]; cnt++; }
  }
  long long oi = (long long)(nb + s) * D_ + d;
  out[oi] += acc / (float)(cnt > 0 ? cnt : 1);
}

// ---------------- host ----------------
extern "C" void kernel_launch(void* const* d_in, const int* in_sizes, int n_in,
                              void* d_out, int out_size, void* d_ws, size_t ws_size,
                              hipStream_t stream) {
  const int*   visits  = (const int*)d_in[0];
  const float* deltas  = (const float*)d_in[1];
  const int*   pad_idx = (const int*)d_in[2];
  const float* X_hyp   = (const float*)d_in[3];
  const float* kernels = (const float*)d_in[4];
  const float* proj_W  = (const float*)d_in[5];
  const float* proj_b  = (const float*)d_in[6];
  const float* Wq = (const float*)d_in[7];
  const float* Wk = (const float*)d_in[8];
  const float* Wv = (const float*)d_in[9];
  const float* Wo = (const float*)d_in[10];
  const float* bq = (const float*)d_in[11];
  const float* bk = (const float*)d_in[12];
  const float* bv = (const float*)d_in[13];
  const float* bo = (const float*)d_in[14];
  const float* ff_W1 = (const float*)d_in[15];
  const float* ff_b1 = (const float*)d_in[16];
  const float* ff_W2 = (const float*)d_in[17];
  const float* ff_b2 = (const float*)d_in[18];
  const float* ln1_g = (const float*)d_in[19];
  const float* ln1_b = (const float*)d_in[20];
  const float* ln2_g = (const float*)d_in[21];
  const float* ln2_b = (const float*)d_in[22];
  const float* tf_W  = (const float*)d_in[23];
  const float* tf_b  = (const float*)d_in[24];
  const float* tp_W  = (const float*)d_in[25];
  const float* tp_b  = (const float*)d_in[26];
  float* out = (float*)d_out;

  char* ws = (char*)d_ws;
  constexpr long long MB = 1ll << 20;
  // weights (fp16, transposed) — ~0.9MB
  f16*   projT = (f16*)(ws);            // [3][128][128]
  f16*   qkvT  = (f16*)(ws + 98304);    // [2][3][128][128]
  f16*   woT   = (f16*)(ws + 294912);   // [2][128][128]
  f16*   w1T   = (f16*)(ws + 360448);   // [2][512][128]
  f16*   w2T   = (f16*)(ws + 622592);   // [2][128][512]
  f16*   tpT   = (f16*)(ws + 884736);   // [128][128]
  float* bqkv  = (float*)(ws + 917504); // [2][384]
  float* Z0    = (float*)(ws + 1 * MB); // [4096][128] f32
  f16*   ycatT = (f16*)(ws + 3 * MB);   // [3][128][4096] f16
  float* x     = (float*)(ws + 6 * MB); // [4096][128] f32
  char*  big   = ws + 8 * MB;           // 24MB region, phase-aliased:
  float* Hp    = (float*)big;           //   diffusion partials [12][4096][128]
  f16*   qk_h  = (f16*)big;             //   q,k fp16 [2][4096][128]
  f16*   vT    = (f16*)(big + 2 * MB);  //   v^T fp16 [128][4096]
  float* o_    = (float*)(big + 3 * MB);//   attn out f32
  float* oW    = (float*)(big + 5 * MB);//   o@Wo f32
  float* t_    = (float*)big;           //   FF mid [4096][512] f32
  float* f_    = (float*)(big + 8 * MB);//   FF out f32
  float* S_    = (float*)big;           //   time feats [16384][128] f32
  (void)ws_size; (void)in_sizes; (void)n_in; (void)out_size;

  // 1) convert weights
  CvtTasks T; int ntk = 0;
  auto addT = [&](const float* s, void* d, int R, int C, int kind) { T.t[ntk++] = {s, d, R, C, kind}; };
  for (int k = 0; k < 3; k++) addT(proj_W + k * 16384, projT + k * 16384, 128, 128, 0);
  for (int i = 0; i < 2; i++) {
    addT(Wq + i * 16384, qkvT + i * 49152 + 0,     128, 128, 0);
    addT(Wk + i * 16384, qkvT + i * 49152 + 16384, 128, 128, 0);
    addT(Wv + i * 16384, qkvT + i * 49152 + 32768, 128, 128, 0);
    addT(Wo + i * 16384, woT + i * 16384, 128, 128, 0);
    addT(ff_W1 + i * 65536, w1T + i * 65536, 128, 512, 0);
    addT(ff_W2 + i * 65536, w2T + i * 65536, 512, 128, 0);
    addT(bq + i * 128, bqkv + i * 384 + 0,   1, 128, 1);
    addT(bk + i * 128, bqkv + i * 384 + 128, 1, 128, 1);
    addT(bv + i * 128, bqkv + i * 384 + 256, 1, 128, 1);
  }
  addT(tp_W, tpT, 128, 128, 0);
  T.n = ntk;
  cvt_kernel<<<256, 256, 0, stream>>>(T);

  // 2) logmap0
  logmap_kernel<<<V_ / 4, 256, 0, stream>>>(X_hyp, Z0);

  // 3) Ycat_k = Z0 @ P_k  (write transposed fp16 [k][128][4096])
  {
    GemmP g{};
    g.A = Z0; g.lda = 128;
    g.BT = projT; g.ldbt = 128; g.bt_z = 16384;
    g.CHT = ycatT; g.ldcht = V_; g.cht_z = (long long)128 * V_;
    g.K = 128;
    gemm_kernel<0, false, false, true><<<dim3(64, 1, 3), 256, 0, stream>>>(g);
  }
  // 4) H partials: Hp[z*4+y] = kernels[z][:, y-chunk] @ Ycat[z][y-chunk, :]
  {
    GemmP g{};
    g.A = kernels; g.lda = V_; g.a_y = 1024; g.a_z = (long long)V_ * V_;
    g.BT = ycatT;  g.ldbt = V_; g.bt_y = 1024; g.bt_z = (long long)128 * V_;
    g.C = Hp; g.ldc = 128; g.c_y = (long long)V_ * D_; g.c_z = 4ll * V_ * D_;
    g.K = 1024;
    gemm_kernel<0, true, false, false><<<dim3(64, 4, 3), 256, 0, stream>>>(g);
  }
  // 5) x = proj_b + sum Hp
  combine_kernel<<<V_ * D_ / 256, 256, 0, stream>>>(Hp, proj_b, x);

  // 6) transformer layers
  for (int i = 0; i < 2; i++) {
    { // q,k (fp16 out)
      GemmP g{};
      g.A = x; g.lda = 128;
      g.BT = qkvT + i * 49152; g.ldbt = 128; g.bt_z = 16384;
      g.bias = bqkv + i * 384; g.bias_z = 128;
      g.CH = qk_h; g.ldch = 128; g.ch_z = (long long)V_ * D_;
      g.K = 128;
      gemm_kernel<0, false, true, false><<<dim3(64, 1, 2), 256, 0, stream>>>(g);
    }
    { // v (transposed fp16 out)
      GemmP g{};
      g.A = x; g.lda = 128;
      g.BT = qkvT + i * 49152 + 32768; g.ldbt = 128;
      g.bias = bqkv + i * 384 + 256;
      g.CHT = vT; g.ldcht = V_;
      g.K = 128;
      gemm_kernel<0, false, false, true><<<dim3(64, 1, 1), 256, 0, stream>>>(g);
    }
    attn_kernel<<<dim3(V_ / 64, 4), 256, 0, stream>>>(qk_h, qk_h + (long long)V_ * D_, vT, o_);
    { // o @ Wo + bo
      GemmP g{};
      g.A = o_; g.lda = 128;
      g.BT = woT + i * 16384; g.ldbt = 128;
      g.bias = bo + i * 128;
      g.C = oW; g.ldc = 128;
      g.K = 128;
      gemm_kernel<0, true, false, false><<<dim3(64, 1, 1), 256, 0, stream>>>(g);
    }
    ln_kernel<<<V_ / 4, 256, 0, stream>>>(x, oW, ln1_g + i * 128, ln1_b + i * 128);
    { // FF1 + exact GELU
      GemmP g{};
      g.A = x; g.lda = 128;
      g.BT = w1T + i * 65536; g.ldbt = 128; g.bt_y = 128 * 128;
      g.bias = ff_b1 + i * 512; g.bias_y = 128;
      g.C = t_; g.ldc = 512; g.c_y = 128;
      g.K = 128;
      gemm_kernel<1, true, false, false><<<dim3(64, 4, 1), 256, 0, stream>>>(g);
    }
    { // FF2
      GemmP g{};
      g.A = t_; g.lda = 512;
      g.BT = w2T + i * 65536; g.ldbt = 512;
      g.bias = ff_b2 + i * 128;
      g.C = f_; g.ldc = 128;
      g.K = 512;
      gemm_kernel<0, true, false, false><<<dim3(64, 1, 1), 256, 0, stream>>>(g);
    }
    ln_kernel<<<V_ / 4, 256, 0, stream>>>(x, f_, ln2_g + i * 128, ln2_b + i * 128);
  }

  // 7) time embedding: out = S @ tp_W + tp_b
  timefeat_kernel<<<NVIS * D_ / 256, 256, 0, stream>>>(deltas, tf_W, tf_b, S_);
  {
    GemmP g{};
    g.A = S_; g.lda = 128;
    g.BT = tpT; g.ldbt = 128;
    g.bias = tp_b;
    g.C = out; g.ldc = 128;
    g.K = 128;
    gemm_kernel<0, true, false, false><<<dim3(NVIS / 64, 1, 1), 256, 0, stream>>>(g);
  }
  // 8) out += masked-mean gather of Hr = x
  gather_kernel<<<NVIS / 2, 256, 0, stream>>>(visits, pad_idx, x, out);
}

// Round 2
// 708.924 us; speedup vs baseline: 1.2584x; 1.2584x over previous
//
#include <hip/hip_runtime.h>

// GraphHyperbolicVisitEncoderGlobal — MI355X fp16-MFMA implementation.
// R2: key-split flash attention (KS=8 -> 8 blocks/CU, full wave occupancy) + combine pass.
// Pipeline: logmap0 -> Ycat_k = Z0@P_k -> H = sum_k kernels[k]@Ycat_k + proj_b
//           -> 2x {QKV, flash-attn, Wo, LN, FF(gelu), LN} -> time-emb GEMM -> gather+mean.
// All matmuls: v_mfma_f32_16x16x32_f16, fp32 accumulate. fp32 softmax/LN/GELU.

using f16 = _Float16;
typedef f16   f16x8 __attribute__((ext_vector_type(8)));
typedef float f32x4 __attribute__((ext_vector_type(4)));

#define V_   4096
#define D_   128
#define NVIS 16384
#define KS_  8     // attention key-splits

union H4 { f16 h[4]; uint2 u; };

// ---------------- weight conversion (fp32 -> fp16 transposed, + bias concat) ----------------
struct CvtTask { const float* src; void* dst; int R, C, kind; }; // kind 0: dst[c*R+r]=(f16)src[r*C+c]; 1: f32 copy
struct CvtTasks { CvtTask t[24]; int n; };

__global__ __launch_bounds__(256) void cvt_kernel(CvtTasks T) {
  int tid0 = blockIdx.x * 256 + threadIdx.x;
  int stride = gridDim.x * 256;
  for (int i = 0; i < T.n; i++) {
    CvtTask tk = T.t[i];
    int total = tk.R * tk.C;
    for (int idx = tid0; idx < total; idx += stride) {
      int r = idx / tk.C, c = idx - r * tk.C;
      if (tk.kind == 0)
        ((f16*)tk.dst)[(long long)c * tk.R + r] = (f16)tk.src[idx];
      else
        ((float*)tk.dst)[idx] = tk.src[idx];
    }
  }
}

// ---------------- logmap0: Z0 = atanh(clip(|x|)) * x / clip(|x|) ----------------
__global__ __launch_bounds__(256) void logmap_kernel(const float* __restrict__ X, float* __restrict__ Z0) {
  int row = blockIdx.x * 4 + (threadIdx.x >> 6);
  int l = threadIdx.x & 63;
  const float* xr = X + (long long)row * D_;
  float a = xr[l], b = xr[l + 64];
  float ss = a * a + b * b;
  #pragma unroll
  for (int m = 1; m < 64; m <<= 1) ss += __shfl_xor(ss, m);
  float nrm = sqrtf(ss);
  float nc = fminf(fmaxf(nrm, 1e-7f), 1.0f - 1e-5f);
  float scale = atanhf(nc) / nc;
  float* zr = Z0 + (long long)row * D_;
  zr[l] = a * scale; zr[l + 64] = b * scale;
}

// ---------------- generic fp16-MFMA GEMM ----------------
// C[M,N](+bias,act) = A[M,K] (fp32, converted while staging) @ B[K,N] (as pre-transposed BT[N][K] fp16)
// block: 256 thr = 4 waves; tile BM=64 x BN=128, BK=64; wave tile 32x64.
struct GemmP {
  const float* A;  long long a_y, a_z;  int lda;
  const f16*  BT;  long long bt_y, bt_z; int ldbt;
  const float* bias; int bias_y, bias_z;         // may be null
  float* C;  long long c_y, c_z;   int ldc;
  f16*  CH;  long long ch_y, ch_z; int ldch;     // row-major fp16 copy
  f16*  CHT; long long cht_y, cht_z; int ldcht;  // transposed fp16 copy [N][M]
  int K;                                          // inner length per block (mult of 64)
};

template<int ACT, bool WC, bool WH, bool WHT>
__global__ __launch_bounds__(256) void gemm_kernel(GemmP p) {
  __shared__ alignas(16) f16 As[64][64];   // XOR-swizzled: col ^= (row&7)<<3
  __shared__ alignas(16) f16 Bs[128][64];  // idem
  int tid = threadIdx.x;
  int m0 = blockIdx.x * 64;
  long long by = blockIdx.y, bz = blockIdx.z;
  const float* A = p.A + by * p.a_y + bz * p.a_z + (long long)m0 * p.lda;
  const f16* BT  = p.BT + by * p.bt_y + bz * p.bt_z;

  int wid = tid >> 6, l = tid & 63;
  int lr = l & 15, lg = l >> 4;
  int wm = (wid & 1) * 32;
  int wn = (wid >> 1) * 64;

  f32x4 acc[2][4] = {};

  for (int kb = 0; kb < p.K; kb += 64) {
    __syncthreads();
    #pragma unroll
    for (int pi = 0; pi < 4; pi++) {            // stage A: 64x64 fp32 -> fp16
      int idx = pi * 256 + tid;
      int r = idx >> 4, c4 = (idx & 15) * 4;
      float4 v = *(const float4*)(A + (long long)r * p.lda + kb + c4);
      int cc = c4 ^ ((r & 7) << 3);
      H4 tmp; tmp.h[0] = (f16)v.x; tmp.h[1] = (f16)v.y; tmp.h[2] = (f16)v.z; tmp.h[3] = (f16)v.w;
      *(uint2*)&As[r][cc] = tmp.u;
    }
    #pragma unroll
    for (int pi = 0; pi < 4; pi++) {            // stage B: 128x64 fp16
      int idx = pi * 256 + tid;
      int n = idx >> 3, g8 = (idx & 7) * 8;
      f16x8 v = *(const f16x8*)(BT + (long long)n * p.ldbt + kb + g8);
      *(f16x8*)&Bs[n][g8 ^ ((n & 7) << 3)] = v;
    }
    __syncthreads();
    #pragma unroll
    for (int kk = 0; kk < 64; kk += 32) {
      f16x8 a[2], b[4];
      #pragma unroll
      for (int mt = 0; mt < 2; mt++) {
        int r = wm + mt * 16 + lr;
        a[mt] = *(const f16x8*)&As[r][(kk + lg * 8) ^ ((r & 7) << 3)];
      }
      #pragma unroll
      for (int nt = 0; nt < 4; nt++) {
        int n = wn + nt * 16 + lr;
        b[nt] = *(const f16x8*)&Bs[n][(kk + lg * 8) ^ ((n & 7) << 3)];
      }
      #pragma unroll
      for (int mt = 0; mt < 2; mt++)
        #pragma unroll
        for (int nt = 0; nt < 4; nt++)
          acc[mt][nt] = __builtin_amdgcn_mfma_f32_16x16x32_f16(a[mt], b[nt], acc[mt][nt], 0, 0, 0);
    }
  }

  const float* bias = p.bias ? p.bias + by * p.bias_y + bz * p.bias_z : nullptr;
  float* C = nullptr; f16* CH = nullptr; f16* CHT = nullptr;
  if (WC)  C   = p.C   + by * p.c_y   + bz * p.c_z   + (long long)m0 * p.ldc;
  if (WH)  CH  = p.CH  + by * p.ch_y  + bz * p.ch_z  + (long long)m0 * p.ldch;
  if (WHT) CHT = p.CHT + by * p.cht_y + bz * p.cht_z;

  #pragma unroll
  for (int nt = 0; nt < 4; nt++) {
    int n = wn + nt * 16 + lr;
    float bv = bias ? bias[n] : 0.0f;
    #pragma unroll
    for (int mt = 0; mt < 2; mt++) {
      H4 th;
      #pragma unroll
      for (int r = 0; r < 4; r++) {
        float val = acc[mt][nt][r] + bv;
        if (ACT == 1) val = 0.5f * val * (1.0f + erff(val * 0.70710678118654752f));
        int m = wm + mt * 16 + lg * 4 + r;
        if (WC) C[(long long)m * p.ldc + n] = val;
        if (WH) CH[(long long)m * p.ldch + n] = (f16)val;
        th.h[r] = (f16)val;
      }
      if (WHT)
        *(uint2*)&CHT[(long long)n * p.ldcht + m0 + wm + mt * 16 + lg * 4] = th.u;
    }
  }
}

// ---------------- combine diffusion partials: x = proj_b + sum Hp ----------------
__global__ __launch_bounds__(256) void combine_kernel(const float* __restrict__ Hp, const float* __restrict__ proj_b,
                                                      float* __restrict__ x) {
  int i = blockIdx.x * 256 + threadIdx.x;
  float s = proj_b[i & 127];
  #pragma unroll
  for (int j = 0; j < 12; j++) s += Hp[(long long)j * (V_ * D_) + i];
  x[i] = s;
}

// ---------------- flash attention, key-split ----------------
// grid (V/64, NH, KS_): block = 64 q-rows of one head over 512 keys; 4 waves, 16 q-rows/wave.
// Writes unnormalized O partials + per-row (m, l) for the combine pass.
__global__ __launch_bounds__(256) void attn_kernel(const f16* __restrict__ qh, const f16* __restrict__ kh,
                                                   const f16* __restrict__ vT,
                                                   float* __restrict__ Op, float* __restrict__ Ml) {
  __shared__ alignas(16) f16 Ks[64][40];      // [key][d] (+8 pad)
  __shared__ alignas(16) f16 Vs[32][72];      // [d][key] (+8 pad)
  __shared__ alignas(16) f16 Ps[4][16][72];   // per-wave P [q][key]
  int tid = threadIdx.x, w = tid >> 6, l = tid & 63, lr = l & 15, lg = l >> 4;
  int h = blockIdx.y, q0 = blockIdx.x * 64, z = blockIdx.z;
  const float sc = 0.17677669529663687f; // 1/sqrt(32)

  f16x8 aq = *(const f16x8*)&qh[(long long)(q0 + w * 16 + lr) * D_ + h * 32 + lg * 8];
  float mrow[4], lsum[4];
  f32x4 oacc[2] = {};
  #pragma unroll
  for (int r = 0; r < 4; r++) { mrow[r] = -1e30f; lsum[r] = 0.f; }
  const f32x4 vzero = {0.f, 0.f, 0.f, 0.f};

  for (int kt = z * (V_ / 64 / KS_); kt < (z + 1) * (V_ / 64 / KS_); kt++) {
    int key0 = kt * 64;
    __syncthreads();
    {
      int key = tid >> 2, g8 = (tid & 3) * 8;
      *(f16x8*)&Ks[key][g8] = *(const f16x8*)&kh[(long long)(key0 + key) * D_ + h * 32 + g8];
      int dd = tid >> 3, kg = (tid & 7) * 8;
      *(f16x8*)&Vs[dd][kg] = *(const f16x8*)&vT[(long long)(h * 32 + dd) * V_ + key0 + kg];
    }
    __syncthreads();
    // S = Q K^T  (tile t covers keys key0+16t..+15)
    f32x4 s[4];
    #pragma unroll
    for (int t = 0; t < 4; t++) {
      f16x8 bk = *(const f16x8*)&Ks[t * 16 + lr][lg * 8];
      s[t] = __builtin_amdgcn_mfma_f32_16x16x32_f16(aq, bk, vzero, 0, 0, 0);
    }
    // online softmax; lane holds rows lg*4+r, key col = 16t+lr
    float pv[4][4];
    #pragma unroll
    for (int r = 0; r < 4; r++) {
      float sv0 = s[0][r] * sc, sv1 = s[1][r] * sc, sv2 = s[2][r] * sc, sv3 = s[3][r] * sc;
      float mx = fmaxf(fmaxf(sv0, sv1), fmaxf(sv2, sv3));
      #pragma unroll
      for (int msk = 1; msk < 16; msk <<= 1) mx = fmaxf(mx, __shfl_xor(mx, msk));
      float mn = fmaxf(mrow[r], mx);
      float alpha = expf(mrow[r] - mn);
      float e0 = expf(sv0 - mn), e1 = expf(sv1 - mn), e2 = expf(sv2 - mn), e3 = expf(sv3 - mn);
      pv[0][r] = e0; pv[1][r] = e1; pv[2][r] = e2; pv[3][r] = e3;
      float rs = e0 + e1 + e2 + e3;
      #pragma unroll
      for (int msk = 1; msk < 16; msk <<= 1) rs += __shfl_xor(rs, msk);
      lsum[r] = lsum[r] * alpha + rs;
      mrow[r] = mn;
      oacc[0][r] *= alpha; oacc[1][r] *= alpha;
    }
    #pragma unroll
    for (int t = 0; t < 4; t++)
      #pragma unroll
      for (int r = 0; r < 4; r++)
        Ps[w][lg * 4 + r][t * 16 + lr] = (f16)pv[t][r];
    // O += P V  (P as A-operand from LDS, V^T as B-operand)
    #pragma unroll
    for (int kc = 0; kc < 2; kc++) {
      f16x8 pa = *(const f16x8*)&Ps[w][lr][kc * 32 + lg * 8];
      #pragma unroll
      for (int t = 0; t < 2; t++) {
        f16x8 bvv = *(const f16x8*)&Vs[t * 16 + lr][kc * 32 + lg * 8];
        oacc[t] = __builtin_amdgcn_mfma_f32_16x16x32_f16(pa, bvv, oacc[t], 0, 0, 0);
      }
    }
  }
  // write unnormalized partials
  #pragma unroll
  for (int t = 0; t < 2; t++)
    #pragma unroll
    for (int r = 0; r < 4; r++) {
      int q = q0 + w * 16 + lg * 4 + r;
      Op[(long long)z * (V_ * D_) + (long long)q * D_ + h * 32 + t * 16 + lr] = oacc[t][r];
    }
  if (lr == 0) {
    #pragma unroll
    for (int r = 0; r < 4; r++) {
      int q = q0 + w * 16 + lg * 4 + r;
      Ml[(z * 4 + h) * V_ + q] = mrow[r];
      Ml[KS_ * 4 * V_ + (z * 4 + h) * V_ + q] = lsum[r];
    }
  }
}

// ---------------- merge key-split partials ----------------
__global__ __launch_bounds__(256) void attn_combine(const float* __restrict__ Op, const float* __restrict__ Ml,
                                                    float* __restrict__ o) {
  int i = blockIdx.x * 256 + threadIdx.x;
  int q = i >> 7, h = (i & 127) >> 5;
  float mv[KS_], lv[KS_];
  float m = -1e30f;
  #pragma unroll
  for (int s = 0; s < KS_; s++) {
    mv[s] = Ml[(s * 4 + h) * V_ + q];
    lv[s] = Ml[KS_ * 4 * V_ + (s * 4 + h) * V_ + q];
    m = fmaxf(m, mv[s]);
  }
  float L = 0.f, O = 0.f;
  #pragma unroll
  for (int s = 0; s < KS_; s++) {
    float wgt = expf(mv[s] - m);
    L += wgt * lv[s];
    O += wgt * Op[(long long)s * (V_ * D_) + i];
  }
  o[i] = O / L;
}

// ---------------- residual + LayerNorm (in-place on x) ----------------
__global__ __launch_bounds__(256) void ln_kernel(float* __restrict__ x, const float* __restrict__ add,
                                                 const float* __restrict__ g, const float* __restrict__ b) {
  int row = blockIdx.x * 4 + (threadIdx.x >> 6);
  int l = threadIdx.x & 63;
  long long base = (long long)row * D_;
  float a = x[base + l] + add[base + l];
  float c = x[base + l + 64] + add[base + l + 64];
  float s = a + c, ss = a * a + c * c;
  #pragma unroll
  for (int m = 1; m < 64; m <<= 1) { s += __shfl_xor(s, m); ss += __shfl_xor(ss, m); }
  float mean = s * (1.0f / 128.0f);
  float var = ss * (1.0f / 128.0f) - mean * mean;
  float rstd = rsqrtf(var + 1e-5f);
  x[base + l]      = (a - mean) * rstd * g[l] + b[l];
  x[base + l + 64] = (c - mean) * rstd * g[l + 64] + b[l + 64];
}

// ---------------- time features: S = 1 - tanh(deltas/180*tf_W + tf_b)^2 ----------------
__global__ __launch_bounds__(256) void timefeat_kernel(const float* __restrict__ deltas, const float* __restrict__ tf_W,
                                                       const float* __restrict__ tf_b, float* __restrict__ S) {
  int i = blockIdx.x * 256 + threadIdx.x;
  int n = i >> 7, d = i & 127;
  float fr = deltas[n] * (1.0f / 180.0f) * tf_W[d] + tf_b[d];
  float t = tanhf(fr);
  S[i] = 1.0f - t * t;
}

// ---------------- ragged gather + masked mean; out += vis ----------------
__global__ __launch_bounds__(256) void gather_kernel(const int* __restrict__ visits, const int* __restrict__ pad_ptr,
                                                     const float* __restrict__ Hr, float* __restrict__ out) {
  __shared__ int vis[2][32];
  int tid = threadIdx.x;
  int pad = *pad_ptr;
  int nb = blockIdx.x * 2;
  if (tid < 64) { int s = tid >> 5, c = tid & 31; vis[s][c] = visits[(long long)(nb + s) * 32 + c]; }
  __syncthreads();
  int s = tid >> 7, d = tid & 127;
  float acc = 0.f; int cnt = 0;
  #pragma unroll 8
  for (int c = 0; c < 32; c++) {
    int idx = vis[s][c];
    if (idx != pad) { acc += Hr[(long long)idx * D_ + d]; cnt++; }
  }
  long long oi = (long long)(nb + s) * D_ + d;
  out[oi] += acc / (float)(cnt > 0 ? cnt : 1);
}

// ---------------- host ----------------
extern "C" void kernel_launch(void* const* d_in, const int* in_sizes, int n_in,
                              void* d_out, int out_size, void* d_ws, size_t ws_size,
                              hipStream_t stream) {
  const int*   visits  = (const int*)d_in[0];
  const float* deltas  = (const float*)d_in[1];
  const int*   pad_idx = (const int*)d_in[2];
  const float* X_hyp   = (const float*)d_in[3];
  const float* kernels = (const float*)d_in[4];
  const float* proj_W  = (const float*)d_in[5];
  const float* proj_b  = (const float*)d_in[6];
  const float* Wq = (const float*)d_in[7];
  const float* Wk = (const float*)d_in[8];
  const float* Wv = (const float*)d_in[9];
  const float* Wo = (const float*)d_in[10];
  const float* bq = (const float*)d_in[11];
  const float* bk = (const float*)d_in[12];
  const float* bv = (const float*)d_in[13];
  const float* bo = (const float*)d_in[14];
  const float* ff_W1 = (const float*)d_in[15];
  const float* ff_b1 = (const float*)d_in[16];
  const float* ff_W2 = (const float*)d_in[17];
  const float* ff_b2 = (const float*)d_in[18];
  const float* ln1_g = (const float*)d_in[19];
  const float* ln1_b = (const float*)d_in[20];
  const float* ln2_g = (const float*)d_in[21];
  const float* ln2_b = (const float*)d_in[22];
  const float* tf_W  = (const float*)d_in[23];
  const float* tf_b  = (const float*)d_in[24];
  const float* tp_W  = (const float*)d_in[25];
  const float* tp_b  = (const float*)d_in[26];
  float* out = (float*)d_out;

  char* ws = (char*)d_ws;
  constexpr long long MB = 1ll << 20;
  // weights (fp16, transposed) — ~0.9MB
  f16*   projT = (f16*)(ws);            // [3][128][128]
  f16*   qkvT  = (f16*)(ws + 98304);    // [2][3][128][128]
  f16*   woT   = (f16*)(ws + 294912);   // [2][128][128]
  f16*   w1T   = (f16*)(ws + 360448);   // [2][512][128]
  f16*   w2T   = (f16*)(ws + 622592);   // [2][128][512]
  f16*   tpT   = (f16*)(ws + 884736);   // [128][128]
  float* bqkv  = (float*)(ws + 917504); // [2][384]
  float* Z0    = (float*)(ws + 1 * MB); // [4096][128] f32
  f16*   ycatT = (f16*)(ws + 3 * MB);   // [3][128][4096] f16
  float* x     = (float*)(ws + 6 * MB); // [4096][128] f32
  char*  big   = ws + 8 * MB;           // 24MB region, phase-aliased:
  float* Hp    = (float*)big;           //   diffusion partials [12][4096][128]
  f16*   qk_h  = (f16*)big;             //   q,k fp16 [2][4096][128]
  f16*   vT    = (f16*)(big + 2 * MB);  //   v^T fp16 [128][4096]
  float* o_    = (float*)(big + 3 * MB);//   attn out f32
  float* oW    = (float*)(big + 5 * MB);//   o@Wo f32
  float* Op    = (float*)(big + 7 * MB);//   attn split partials [8][4096][128] f32 (16MB)
  float* Ml    = (float*)(big + 23 * MB);// attn split (m,l) [2][8][4][4096] f32 (1MB)
  float* t_    = (float*)big;           //   FF mid [4096][512] f32 (8MB)
  float* f_    = (float*)(big + 8 * MB);//   FF out f32
  float* S_    = (float*)big;           //   time feats [16384][128] f32
  (void)ws_size; (void)in_sizes; (void)n_in; (void)out_size;

  // 1) convert weights
  CvtTasks T; int ntk = 0;
  auto addT = [&](const float* s, void* d, int R, int C, int kind) { T.t[ntk++] = {s, d, R, C, kind}; };
  for (int k = 0; k < 3; k++) addT(proj_W + k * 16384, projT + k * 16384, 128, 128, 0);
  for (int i = 0; i < 2; i++) {
    addT(Wq + i * 16384, qkvT + i * 49152 + 0,     128, 128, 0);
    addT(Wk + i * 16384, qkvT + i * 49152 + 16384, 128, 128, 0);
    addT(Wv + i * 16384, qkvT + i * 49152 + 32768, 128, 128, 0);
    addT(Wo + i * 16384, woT + i * 16384, 128, 128, 0);
    addT(ff_W1 + i * 65536, w1T + i * 65536, 128, 512, 0);
    addT(ff_W2 + i * 65536, w2T + i * 65536, 512, 128, 0);
    addT(bq + i * 128, bqkv + i * 384 + 0,   1, 128, 1);
    addT(bk + i * 128, bqkv + i * 384 + 128, 1, 128, 1);
    addT(bv + i * 128, bqkv + i * 384 + 256, 1, 128, 1);
  }
  addT(tp_W, tpT, 128, 128, 0);
  T.n = ntk;
  cvt_kernel<<<256, 256, 0, stream>>>(T);

  // 2) logmap0
  logmap_kernel<<<V_ / 4, 256, 0, stream>>>(X_hyp, Z0);

  // 3) Ycat_k = Z0 @ P_k  (write transposed fp16 [k][128][4096])
  {
    GemmP g{};
    g.A = Z0; g.lda = 128;
    g.BT = projT; g.ldbt = 128; g.bt_z = 16384;
    g.CHT = ycatT; g.ldcht = V_; g.cht_z = (long long)128 * V_;
    g.K = 128;
    gemm_kernel<0, false, false, true><<<dim3(64, 1, 3), 256, 0, stream>>>(g);
  }
  // 4) H partials: Hp[z*4+y] = kernels[z][:, y-chunk] @ Ycat[z][y-chunk, :]
  {
    GemmP g{};
    g.A = kernels; g.lda = V_; g.a_y = 1024; g.a_z = (long long)V_ * V_;
    g.BT = ycatT;  g.ldbt = V_; g.bt_y = 1024; g.bt_z = (long long)128 * V_;
    g.C = Hp; g.ldc = 128; g.c_y = (long long)V_ * D_; g.c_z = 4ll * V_ * D_;
    g.K = 1024;
    gemm_kernel<0, true, false, false><<<dim3(64, 4, 3), 256, 0, stream>>>(g);
  }
  // 5) x = proj_b + sum Hp
  combine_kernel<<<V_ * D_ / 256, 256, 0, stream>>>(Hp, proj_b, x);

  // 6) transformer layers
  for (int i = 0; i < 2; i++) {
    { // q,k (fp16 out)
      GemmP g{};
      g.A = x; g.lda = 128;
      g.BT = qkvT + i * 49152; g.ldbt = 128; g.bt_z = 16384;
      g.bias = bqkv + i * 384; g.bias_z = 128;
      g.CH = qk_h; g.ldch = 128; g.ch_z = (long long)V_ * D_;
      g.K = 128;
      gemm_kernel<0, false, true, false><<<dim3(64, 1, 2), 256, 0, stream>>>(g);
    }
    { // v (transposed fp16 out)
      GemmP g{};
      g.A = x; g.lda = 128;
      g.BT = qkvT + i * 49152 + 32768; g.ldbt = 128;
      g.bias = bqkv + i * 384 + 256;
      g.CHT = vT; g.ldcht = V_;
      g.K = 128;
      gemm_kernel<0, false, false, true><<<dim3(64, 1, 1), 256, 0, stream>>>(g);
    }
    attn_kernel<<<dim3(V_ / 64, 4, KS_), 256, 0, stream>>>(qk_h, qk_h + (long long)V_ * D_, vT, Op, Ml);
    attn_combine<<<V_ * D_ / 256, 256, 0, stream>>>(Op, Ml, o_);
    { // o @ Wo + bo
      GemmP g{};
      g.A = o_; g.lda = 128;
      g.BT = woT + i * 16384; g.ldbt = 128;
      g.bias = bo + i * 128;
      g.C = oW; g.ldc = 128;
      g.K = 128;
      gemm_kernel<0, true, false, false><<<dim3(64, 1, 1), 256, 0, stream>>>(g);
    }
    ln_kernel<<<V_ / 4, 256, 0, stream>>>(x, oW, ln1_g + i * 128, ln1_b + i * 128);
    { // FF1 + exact GELU
      GemmP g{};
      g.A = x; g.lda = 128;
      g.BT = w1T + i * 65536; g.ldbt = 128; g.bt_y = 128 * 128;
      g.bias = ff_b1 + i * 512; g.bias_y = 128;
      g.C = t_; g.ldc = 512; g.c_y = 128;
      g.K = 128;
      gemm_kernel<1, true, false, false><<<dim3(64, 4, 1), 256, 0, stream>>>(g);
    }
    { // FF2
      GemmP g{};
      g.A = t_; g.lda = 512;
      g.BT = w2T + i * 65536; g.ldbt = 512;
      g.bias = ff_b2 + i * 128;
      g.C = f_; g.ldc = 128;
      g.K = 512;
      gemm_kernel<0, true, false, false><<<dim3(64, 1, 1), 256, 0, stream>>>(g);
    }
    ln_kernel<<<V_ / 4, 256, 0, stream>>>(x, f_, ln2_g + i * 128, ln2_b + i * 128);
  }

  // 7) time embedding: out = S @ tp_W + tp_b
  timefeat_kernel<<<NVIS * D_ / 256, 256, 0, stream>>>(deltas, tf_W, tf_b, S_);
  {
    GemmP g{};
    g.A = S_; g.lda = 128;
    g.BT = tpT; g.ldbt = 128;
    g.bias = tp_b;
    g.C = out; g.ldc = 128;
    g.K = 128;
    gemm_kernel<0, true, false, false><<<dim3(NVIS / 64, 1, 1), 256, 0, stream>>>(g);
  }
  // 8) out += masked-mean gather of Hr = x
  gather_kernel<<<NVIS / 2, 256, 0, stream>>>(visits, pad_idx, x, out);
}

// Round 3
// 639.969 us; speedup vs baseline: 1.3940x; 1.1077x over previous
//
#include <hip/hip_runtime.h>

// GraphHyperbolicVisitEncoderGlobal — MI355X fp16-MFMA implementation.
// R3: swapped-operand QK^T (lane-local softmax rows, 2 shfl instead of 32),
//     merged QKV launch, residual+LN fused into Wo/FF2 GEMM epilogues.

using f16 = _Float16;
typedef f16   f16x8 __attribute__((ext_vector_type(8)));
typedef float f32x4 __attribute__((ext_vector_type(4)));

#define V_   4096
#define D_   128
#define NVIS 16384
#define KS_  8     // attention key-splits

union H4 { f16 h[4]; uint2 u; };

// ---------------- weight conversion (fp32 -> fp16 transposed, + bias concat) ----------------
struct CvtTask { const float* src; void* dst; int R, C, kind; }; // kind 0: dst[c*R+r]=(f16)src[r*C+c]; 1: f32 copy
struct CvtTasks { CvtTask t[24]; int n; };

__global__ __launch_bounds__(256) void cvt_kernel(CvtTasks T) {
  int tid0 = blockIdx.x * 256 + threadIdx.x;
  int stride = gridDim.x * 256;
  for (int i = 0; i < T.n; i++) {
    CvtTask tk = T.t[i];
    int total = tk.R * tk.C;
    for (int idx = tid0; idx < total; idx += stride) {
      int r = idx / tk.C, c = idx - r * tk.C;
      if (tk.kind == 0)
        ((f16*)tk.dst)[(long long)c * tk.R + r] = (f16)tk.src[idx];
      else
        ((float*)tk.dst)[idx] = tk.src[idx];
    }
  }
}

// ---------------- logmap0 ----------------
__global__ __launch_bounds__(256) void logmap_kernel(const float* __restrict__ X, float* __restrict__ Z0) {
  int row = blockIdx.x * 4 + (threadIdx.x >> 6);
  int l = threadIdx.x & 63;
  const float* xr = X + (long long)row * D_;
  float a = xr[l], b = xr[l + 64];
  float ss = a * a + b * b;
  #pragma unroll
  for (int m = 1; m < 64; m <<= 1) ss += __shfl_xor(ss, m);
  float nrm = sqrtf(ss);
  float nc = fminf(fmaxf(nrm, 1e-7f), 1.0f - 1e-5f);
  float scale = atanhf(nc) / nc;
  float* zr = Z0 + (long long)row * D_;
  zr[l] = a * scale; zr[l + 64] = b * scale;
}

// ---------------- generic fp16-MFMA GEMM ----------------
// C[M,N](+bias,act) = A[M,K] (fp32, converted while staging) @ BT[N][K] fp16.
// block 256 thr = 4 waves; tile BM=64 x BN=128, BK=64; wave tile 32x64.
// EPI: 0 = f32 C + bias; 1 = f32 C + bias + exact GELU; 3 = fp16 transposed CHT;
//      4 = QKV (bz<2 -> fp16 CH, bz==2 -> fp16 CHT); 5 = bias + residual + LayerNorm -> f32 C (in-place x)
struct GemmP {
  const float* A;  long long a_y, a_z;  int lda;
  const f16*  BT;  long long bt_y, bt_z; int ldbt;
  const float* bias; int bias_y, bias_z;         // may be null
  float* C;  long long c_y, c_z;   int ldc;
  f16*  CH;  long long ch_y, ch_z; int ldch;     // row-major fp16
  f16*  CHT; long long cht_y, cht_z; int ldcht;  // transposed fp16 [N][M]
  const float* lng; const float* lnb;            // EPI 5
  int K;
};

template<int EPI>
__global__ __launch_bounds__(256) void gemm_kernel(GemmP p) {
  __shared__ alignas(16) f16 As[64][64];   // XOR-swizzled: col ^= (row&7)<<3
  __shared__ alignas(16) f16 Bs[128][64];
  __shared__ float lnred[2][64][2];        // EPI5 row stats (sum, sumsq) per n-half
  int tid = threadIdx.x;
  int m0 = blockIdx.x * 64;
  long long by = blockIdx.y, bz = blockIdx.z;
  const float* A = p.A + by * p.a_y + bz * p.a_z + (long long)m0 * p.lda;
  const f16* BT  = p.BT + by * p.bt_y + bz * p.bt_z;

  int wid = tid >> 6, l = tid & 63;
  int lr = l & 15, lg = l >> 4;
  int wm = (wid & 1) * 32;
  int wn = (wid >> 1) * 64;

  f32x4 acc[2][4] = {};

  for (int kb = 0; kb < p.K; kb += 64) {
    __syncthreads();
    #pragma unroll
    for (int pi = 0; pi < 4; pi++) {            // stage A: 64x64 fp32 -> fp16
      int idx = pi * 256 + tid;
      int r = idx >> 4, c4 = (idx & 15) * 4;
      float4 v = *(const float4*)(A + (long long)r * p.lda + kb + c4);
      int cc = c4 ^ ((r & 7) << 3);
      H4 tmp; tmp.h[0] = (f16)v.x; tmp.h[1] = (f16)v.y; tmp.h[2] = (f16)v.z; tmp.h[3] = (f16)v.w;
      *(uint2*)&As[r][cc] = tmp.u;
    }
    #pragma unroll
    for (int pi = 0; pi < 4; pi++) {            // stage B: 128x64 fp16
      int idx = pi * 256 + tid;
      int n = idx >> 3, g8 = (idx & 7) * 8;
      f16x8 v = *(const f16x8*)(BT + (long long)n * p.ldbt + kb + g8);
      *(f16x8*)&Bs[n][g8 ^ ((n & 7) << 3)] = v;
    }
    __syncthreads();
    #pragma unroll
    for (int kk = 0; kk < 64; kk += 32) {
      f16x8 a[2], b[4];
      #pragma unroll
      for (int mt = 0; mt < 2; mt++) {
        int r = wm + mt * 16 + lr;
        a[mt] = *(const f16x8*)&As[r][(kk + lg * 8) ^ ((r & 7) << 3)];
      }
      #pragma unroll
      for (int nt = 0; nt < 4; nt++) {
        int n = wn + nt * 16 + lr;
        b[nt] = *(const f16x8*)&Bs[n][(kk + lg * 8) ^ ((n & 7) << 3)];
      }
      #pragma unroll
      for (int mt = 0; mt < 2; mt++)
        #pragma unroll
        for (int nt = 0; nt < 4; nt++)
          acc[mt][nt] = __builtin_amdgcn_mfma_f32_16x16x32_f16(a[mt], b[nt], acc[mt][nt], 0, 0, 0);
    }
  }

  const float* bias = p.bias ? p.bias + by * p.bias_y + bz * p.bias_z : nullptr;

  if constexpr (EPI == 5) {
    // residual + LayerNorm fused: val = acc + bias + C[m][n]; C[m][n] = LN(val)
    float* C = p.C + (long long)m0 * p.ldc;
    #pragma unroll
    for (int nt = 0; nt < 4; nt++) {
      int n = wn + nt * 16 + lr;
      float bv = bias ? bias[n] : 0.0f;
      #pragma unroll
      for (int mt = 0; mt < 2; mt++)
        #pragma unroll
        for (int r = 0; r < 4; r++) {
          int m = wm + mt * 16 + lg * 4 + r;
          acc[mt][nt][r] += bv + C[(long long)m * p.ldc + n];
        }
    }
    #pragma unroll
    for (int mt = 0; mt < 2; mt++)
      #pragma unroll
      for (int r = 0; r < 4; r++) {
        float s = 0.f, ss = 0.f;
        #pragma unroll
        for (int nt = 0; nt < 4; nt++) { float v = acc[mt][nt][r]; s += v; ss += v * v; }
        #pragma unroll
        for (int msk = 1; msk < 16; msk <<= 1) { s += __shfl_xor(s, msk); ss += __shfl_xor(ss, msk); }
        if (lr == 0) {
          int row = wm + mt * 16 + lg * 4 + r;
          lnred[wid >> 1][row][0] = s; lnred[wid >> 1][row][1] = ss;
        }
      }
    __syncthreads();
    #pragma unroll
    for (int mt = 0; mt < 2; mt++)
      #pragma unroll
      for (int r = 0; r < 4; r++) {
        int row = wm + mt * 16 + lg * 4 + r;
        float s  = lnred[0][row][0] + lnred[1][row][0];
        float ss = lnred[0][row][1] + lnred[1][row][1];
        float mean = s * (1.0f / 128.0f);
        float rstd = rsqrtf(ss * (1.0f / 128.0f) - mean * mean + 1e-5f);
        #pragma unroll
        for (int nt = 0; nt < 4; nt++) {
          int n = wn + nt * 16 + lr;
          C[(long long)row * p.ldc + n] = (acc[mt][nt][r] - mean) * rstd * p.lng[n] + p.lnb[n];
        }
      }
    return;
  } else {
    bool do_c  = (EPI == 0 || EPI == 1);
    bool do_h  = (EPI == 4 && bz < 2);
    bool do_ht = (EPI == 3) || (EPI == 4 && bz == 2);
    float* C = nullptr; f16* CH = nullptr; f16* CHT = nullptr;
    if (do_c)  C   = p.C   + by * p.c_y   + bz * p.c_z   + (long long)m0 * p.ldc;
    if (do_h)  CH  = p.CH  + by * p.ch_y  + bz * p.ch_z  + (long long)m0 * p.ldch;
    if (do_ht) CHT = p.CHT + by * p.cht_y + bz * p.cht_z;

    #pragma unroll
    for (int nt = 0; nt < 4; nt++) {
      int n = wn + nt * 16 + lr;
      float bv = bias ? bias[n] : 0.0f;
      #pragma unroll
      for (int mt = 0; mt < 2; mt++) {
        H4 th;
        #pragma unroll
        for (int r = 0; r < 4; r++) {
          float val = acc[mt][nt][r] + bv;
          if (EPI == 1) val = 0.5f * val * (1.0f + erff(val * 0.70710678118654752f));
          int m = wm + mt * 16 + lg * 4 + r;
          if (do_c) C[(long long)m * p.ldc + n] = val;
          if (do_h) CH[(long long)m * p.ldch + n] = (f16)val;
          th.h[r] = (f16)val;
        }
        if (do_ht)
          *(uint2*)&CHT[(long long)n * p.ldcht + m0 + wm + mt * 16 + lg * 4] = th.u;
      }
    }
  }
}

// ---------------- combine diffusion partials: x = proj_b + sum Hp ----------------
__global__ __launch_bounds__(256) void combine_kernel(const float* __restrict__ Hp, const float* __restrict__ proj_b,
                                                      float* __restrict__ x) {
  int i = blockIdx.x * 256 + threadIdx.x;
  float s = proj_b[i & 127];
  #pragma unroll
  for (int j = 0; j < 12; j++) s += Hp[(long long)j * (V_ * D_) + i];
  x[i] = s;
}

// ---------------- flash attention, key-split, swapped-operand QK^T ----------------
// grid (V/64, NH, KS_): 4 waves, 16 q-rows/wave. S^T = mfma(K,Q): lane owns q=lr, 16 keys in-register.
__global__ __launch_bounds__(256) void attn_kernel(const f16* __restrict__ qh, const f16* __restrict__ kh,
                                                   const f16* __restrict__ vT,
                                                   float* __restrict__ Op, float* __restrict__ Ml) {
  __shared__ alignas(16) f16 Ks[64][40];      // [key][d] (+8 pad)
  __shared__ alignas(16) f16 Vs[32][72];      // [d][key] (+8 pad)
  __shared__ alignas(16) f16 Ps[4][16][72];   // per-wave P [q][key]
  int tid = threadIdx.x, w = tid >> 6, l = tid & 63, lr = l & 15, lg = l >> 4;
  int h = blockIdx.y, q0 = blockIdx.x * 64, z = blockIdx.z;
  const float sc = 0.17677669529663687f; // 1/sqrt(32)

  f16x8 aq = *(const f16x8*)&qh[(long long)(q0 + w * 16 + lr) * D_ + h * 32 + lg * 8];
  float mrow = -1e30f, lsum = 0.f;        // softmax state for q = lr (dup across lg)
  f32x4 oacc[2] = {};
  const f32x4 vzero = {0.f, 0.f, 0.f, 0.f};

  for (int kt = z * (V_ / 64 / KS_); kt < (z + 1) * (V_ / 64 / KS_); kt++) {
    int key0 = kt * 64;
    __syncthreads();
    {
      int key = tid >> 2, g8 = (tid & 3) * 8;
      *(f16x8*)&Ks[key][g8] = *(const f16x8*)&kh[(long long)(key0 + key) * D_ + h * 32 + g8];
      int dd = tid >> 3, kg = (tid & 7) * 8;
      *(f16x8*)&Vs[dd][kg] = *(const f16x8*)&vT[(long long)(h * 32 + dd) * V_ + key0 + kg];
    }
    __syncthreads();
    // S^T = K Q^T : st[t][r] = S[key = key0+16t+lg*4+r][q = lr]
    f32x4 st[4];
    #pragma unroll
    for (int t = 0; t < 4; t++) {
      f16x8 bk = *(const f16x8*)&Ks[t * 16 + lr][lg * 8];
      st[t] = __builtin_amdgcn_mfma_f32_16x16x32_f16(bk, aq, vzero, 0, 0, 0);
    }
    float sv[16];
    #pragma unroll
    for (int t = 0; t < 4; t++)
      #pragma unroll
      for (int r = 0; r < 4; r++) sv[t * 4 + r] = st[t][r] * sc;
    // row max: 15 in-lane + butterfly across lg groups
    float mx = sv[0];
    #pragma unroll
    for (int i = 1; i < 16; i++) mx = fmaxf(mx, sv[i]);
    mx = fmaxf(mx, __shfl_xor(mx, 16));
    mx = fmaxf(mx, __shfl_xor(mx, 32));
    float mn = fmaxf(mrow, mx);
    float alpha = expf(mrow - mn);
    mrow = mn;
    float rs = 0.f, pv[16];
    #pragma unroll
    for (int i = 0; i < 16; i++) { pv[i] = expf(sv[i] - mn); rs += pv[i]; }
    rs += __shfl_xor(rs, 16);
    rs += __shfl_xor(rs, 32);
    lsum = lsum * alpha + rs;
    // rescale O (its q = lg*4+r -> broadcast alpha from lane lg*4+r)
    #pragma unroll
    for (int r = 0; r < 4; r++) {
      float ar = __shfl(alpha, lg * 4 + r);
      oacc[0][r] *= ar; oacc[1][r] *= ar;
    }
    // P -> LDS (vectorized: keys 16t+lg*4..+3 contiguous)
    #pragma unroll
    for (int t = 0; t < 4; t++) {
      H4 hh;
      #pragma unroll
      for (int r = 0; r < 4; r++) hh.h[r] = (f16)pv[t * 4 + r];
      *(uint2*)&Ps[w][lr][t * 16 + lg * 4] = hh.u;
    }
    // O += P V (wave-private Ps: no barrier needed)
    #pragma unroll
    for (int kc = 0; kc < 2; kc++) {
      f16x8 pa = *(const f16x8*)&Ps[w][lr][kc * 32 + lg * 8];
      #pragma unroll
      for (int t = 0; t < 2; t++) {
        f16x8 bvv = *(const f16x8*)&Vs[t * 16 + lr][kc * 32 + lg * 8];
        oacc[t] = __builtin_amdgcn_mfma_f32_16x16x32_f16(pa, bvv, oacc[t], 0, 0, 0);
      }
    }
  }
  // write unnormalized partials: oacc q = lg*4+r, d = h*32+16t+lr
  #pragma unroll
  for (int t = 0; t < 2; t++)
    #pragma unroll
    for (int r = 0; r < 4; r++) {
      int q = q0 + w * 16 + lg * 4 + r;
      Op[(long long)z * (V_ * D_) + (long long)q * D_ + h * 32 + t * 16 + lr] = oacc[t][r];
    }
  if (l < 16) {
    int q = q0 + w * 16 + l;
    Ml[(z * 4 + h) * V_ + q] = mrow;
    Ml[KS_ * 4 * V_ + (z * 4 + h) * V_ + q] = lsum;
  }
}

// ---------------- merge key-split partials ----------------
__global__ __launch_bounds__(256) void attn_combine(const float* __restrict__ Op, const float* __restrict__ Ml,
                                                    float* __restrict__ o) {
  int i = blockIdx.x * 256 + threadIdx.x;
  int q = i >> 7, h = (i & 127) >> 5;
  float mv[KS_], lv[KS_];
  float m = -1e30f;
  #pragma unroll
  for (int s = 0; s < KS_; s++) {
    mv[s] = Ml[(s * 4 + h) * V_ + q];
    lv[s] = Ml[KS_ * 4 * V_ + (s * 4 + h) * V_ + q];
    m = fmaxf(m, mv[s]);
  }
  float L = 0.f, O = 0.f;
  #pragma unroll
  for (int s = 0; s < KS_; s++) {
    float wgt = expf(mv[s] - m);
    L += wgt * lv[s];
    O += wgt * Op[(long long)s * (V_ * D_) + i];
  }
  o[i] = O / L;
}

// ---------------- time features ----------------
__global__ __launch_bounds__(256) void timefeat_kernel(const float* __restrict__ deltas, const float* __restrict__ tf_W,
                                                       const float* __restrict__ tf_b, float* __restrict__ S) {
  int i = blockIdx.x * 256 + threadIdx.x;
  int n = i >> 7, d = i & 127;
  float fr = deltas[n] * (1.0f / 180.0f) * tf_W[d] + tf_b[d];
  float t = tanhf(fr);
  S[i] = 1.0f - t * t;
}

// ---------------- ragged gather + masked mean; out += vis ----------------
__global__ __launch_bounds__(256) void gather_kernel(const int* __restrict__ visits, const int* __restrict__ pad_ptr,
                                                     const float* __restrict__ Hr, float* __restrict__ out) {
  __shared__ int vis[2][32];
  int tid = threadIdx.x;
  int pad = *pad_ptr;
  int nb = blockIdx.x * 2;
  if (tid < 64) { int s = tid >> 5, c = tid & 31; vis[s][c] = visits[(long long)(nb + s) * 32 + c]; }
  __syncthreads();
  int s = tid >> 7, d = tid & 127;
  float acc = 0.f; int cnt = 0;
  #pragma unroll 8
  for (int c = 0; c < 32; c++) {
    int idx = vis[s][c];
    if (idx != pad) { acc += Hr[(long long)idx * D_ + d]; cnt++; }
  }
  long long oi = (long long)(nb + s) * D_ + d;
  out[oi] += acc / (float)(cnt > 0 ? cnt : 1);
}

// ---------------- host ----------------
extern "C" void kernel_launch(void* const* d_in, const int* in_sizes, int n_in,
                              void* d_out, int out_size, void* d_ws, size_t ws_size,
                              hipStream_t stream) {
  const int*   visits  = (const int*)d_in[0];
  const float* deltas  = (const float*)d_in[1];
  const int*   pad_idx = (const int*)d_in[2];
  const float* X_hyp   = (const float*)d_in[3];
  const float* kernels = (const float*)d_in[4];
  const float* proj_W  = (const float*)d_in[5];
  const float* proj_b  = (const float*)d_in[6];
  const float* Wq = (const float*)d_in[7];
  const float* Wk = (const float*)d_in[8];
  const float* Wv = (const float*)d_in[9];
  const float* Wo = (const float*)d_in[10];
  const float* bq = (const float*)d_in[11];
  const float* bk = (const float*)d_in[12];
  const float* bv = (const float*)d_in[13];
  const float* bo = (const float*)d_in[14];
  const float* ff_W1 = (const float*)d_in[15];
  const float* ff_b1 = (const float*)d_in[16];
  const float* ff_W2 = (const float*)d_in[17];
  const float* ff_b2 = (const float*)d_in[18];
  const float* ln1_g = (const float*)d_in[19];
  const float* ln1_b = (const float*)d_in[20];
  const float* ln2_g = (const float*)d_in[21];
  const float* ln2_b = (const float*)d_in[22];
  const float* tf_W  = (const float*)d_in[23];
  const float* tf_b  = (const float*)d_in[24];
  const float* tp_W  = (const float*)d_in[25];
  const float* tp_b  = (const float*)d_in[26];
  float* out = (float*)d_out;

  char* ws = (char*)d_ws;
  constexpr long long MB = 1ll << 20;
  f16*   projT = (f16*)(ws);            // [3][128][128]
  f16*   qkvT  = (f16*)(ws + 98304);    // [2][3][128][128]
  f16*   woT   = (f16*)(ws + 294912);   // [2][128][128]
  f16*   w1T   = (f16*)(ws + 360448);   // [2][512][128]
  f16*   w2T   = (f16*)(ws + 622592);   // [2][128][512]
  f16*   tpT   = (f16*)(ws + 884736);   // [128][128]
  float* bqkv  = (float*)(ws + 917504); // [2][384]
  float* Z0    = (float*)(ws + 1 * MB); // [4096][128] f32
  f16*   ycatT = (f16*)(ws + 3 * MB);   // [3][128][4096] f16
  float* x     = (float*)(ws + 6 * MB); // [4096][128] f32
  char*  big   = ws + 8 * MB;           // phase-aliased:
  float* Hp    = (float*)big;           //   diffusion partials [12][4096][128]
  f16*   qk_h  = (f16*)big;             //   q,k fp16 [2][4096][128] (2MB)
  f16*   vT    = (f16*)(big + 2 * MB);  //   v^T fp16 [128][4096] (1MB)
  float* o_    = (float*)(big + 3 * MB);//   attn out f32 (2MB)
  float* Op    = (float*)(big + 7 * MB);//   attn split partials [8][4096][128] f32 (16MB)
  float* Ml    = (float*)(big + 23 * MB);// attn split (m,l) [2][8][4][4096] f32 (1MB)
  float* t_    = (float*)big;           //   FF mid [4096][512] f32 (8MB)
  float* S_    = (float*)big;           //   time feats [16384][128] f32
  (void)ws_size; (void)in_sizes; (void)n_in; (void)out_size;

  // 1) convert weights
  CvtTasks T; int ntk = 0;
  auto addT = [&](const float* s, void* d, int R, int C, int kind) { T.t[ntk++] = {s, d, R, C, kind}; };
  for (int k = 0; k < 3; k++) addT(proj_W + k * 16384, projT + k * 16384, 128, 128, 0);
  for (int i = 0; i < 2; i++) {
    addT(Wq + i * 16384, qkvT + i * 49152 + 0,     128, 128, 0);
    addT(Wk + i * 16384, qkvT + i * 49152 + 16384, 128, 128, 0);
    addT(Wv + i * 16384, qkvT + i * 49152 + 32768, 128, 128, 0);
    addT(Wo + i * 16384, woT + i * 16384, 128, 128, 0);
    addT(ff_W1 + i * 65536, w1T + i * 65536, 128, 512, 0);
    addT(ff_W2 + i * 65536, w2T + i * 65536, 512, 128, 0);
    addT(bq + i * 128, bqkv + i * 384 + 0,   1, 128, 1);
    addT(bk + i * 128, bqkv + i * 384 + 128, 1, 128, 1);
    addT(bv + i * 128, bqkv + i * 384 + 256, 1, 128, 1);
  }
  addT(tp_W, tpT, 128, 128, 0);
  T.n = ntk;
  cvt_kernel<<<256, 256, 0, stream>>>(T);

  // 2) logmap0
  logmap_kernel<<<V_ / 4, 256, 0, stream>>>(X_hyp, Z0);

  // 3) Ycat_k = Z0 @ P_k  (transposed fp16 out)
  {
    GemmP g{};
    g.A = Z0; g.lda = 128;
    g.BT = projT; g.ldbt = 128; g.bt_z = 16384;
    g.CHT = ycatT; g.ldcht = V_; g.cht_z = (long long)128 * V_;
    g.K = 128;
    gemm_kernel<3><<<dim3(64, 1, 3), 256, 0, stream>>>(g);
  }
  // 4) diffusion partials
  {
    GemmP g{};
    g.A = kernels; g.lda = V_; g.a_y = 1024; g.a_z = (long long)V_ * V_;
    g.BT = ycatT;  g.ldbt = V_; g.bt_y = 1024; g.bt_z = (long long)128 * V_;
    g.C = Hp; g.ldc = 128; g.c_y = (long long)V_ * D_; g.c_z = 4ll * V_ * D_;
    g.K = 1024;
    gemm_kernel<0><<<dim3(64, 4, 3), 256, 0, stream>>>(g);
  }
  // 5) x = proj_b + sum Hp
  combine_kernel<<<V_ * D_ / 256, 256, 0, stream>>>(Hp, proj_b, x);

  // 6) transformer layers
  for (int i = 0; i < 2; i++) {
    { // q,k,v in one launch (z: 0=q row-major, 1=k row-major, 2=v transposed)
      GemmP g{};
      g.A = x; g.lda = 128;
      g.BT = qkvT + i * 49152; g.ldbt = 128; g.bt_z = 16384;
      g.bias = bqkv + i * 384; g.bias_z = 128;
      g.CH = qk_h; g.ldch = 128; g.ch_z = (long long)V_ * D_;
      g.CHT = vT; g.ldcht = V_; g.cht_z = 0;
      g.K = 128;
      gemm_kernel<4><<<dim3(64, 1, 3), 256, 0, stream>>>(g);
    }
    attn_kernel<<<dim3(V_ / 64, 4, KS_), 256, 0, stream>>>(qk_h, qk_h + (long long)V_ * D_, vT, Op, Ml);
    attn_combine<<<V_ * D_ / 256, 256, 0, stream>>>(Op, Ml, o_);
    { // x = LN(x + o@Wo + bo)
      GemmP g{};
      g.A = o_; g.lda = 128;
      g.BT = woT + i * 16384; g.ldbt = 128;
      g.bias = bo + i * 128;
      g.C = x; g.ldc = 128;
      g.lng = ln1_g + i * 128; g.lnb = ln1_b + i * 128;
      g.K = 128;
      gemm_kernel<5><<<dim3(64, 1, 1), 256, 0, stream>>>(g);
    }
    { // FF1 + exact GELU
      GemmP g{};
      g.A = x; g.lda = 128;
      g.BT = w1T + i * 65536; g.ldbt = 128; g.bt_y = 128 * 128;
      g.bias = ff_b1 + i * 512; g.bias_y = 128;
      g.C = t_; g.ldc = 512; g.c_y = 128;
      g.K = 128;
      gemm_kernel<1><<<dim3(64, 4, 1), 256, 0, stream>>>(g);
    }
    { // x = LN(x + t@W2 + b2)
      GemmP g{};
      g.A = t_; g.lda = 512;
      g.BT = w2T + i * 65536; g.ldbt = 512;
      g.bias = ff_b2 + i * 128;
      g.C = x; g.ldc = 128;
      g.lng = ln2_g + i * 128; g.lnb = ln2_b + i * 128;
      g.K = 512;
      gemm_kernel<5><<<dim3(64, 1, 1), 256, 0, stream>>>(g);
    }
  }

  // 7) time embedding: out = S @ tp_W + tp_b
  timefeat_kernel<<<NVIS * D_ / 256, 256, 0, stream>>>(deltas, tf_W, tf_b, S_);
  {
    GemmP g{};
    g.A = S_; g.lda = 128;
    g.BT = tpT; g.ldbt = 128;
    g.bias = tp_b;
    g.C = out; g.ldc = 128;
    g.K = 128;
    gemm_kernel<0><<<dim3(NVIS / 64, 1, 1), 256, 0, stream>>>(g);
  }
  // 8) out += masked-mean gather of Hr = x
  gather_kernel<<<NVIS / 2, 256, 0, stream>>>(visits, pad_idx, x, out);
}